// Round 1
// baseline (558.084 us; speedup 1.0000x reference)
//
#include <hip/hip_runtime.h>

#define NN 50000
#define EE 800000
#define IND 128
#define OUTD 64

// ---------------- Pass A: z = h @ W^T, s1 = z.w1, s2 = z.w2 ----------------
// Block 256 = 4 waves. Each wave processes 16 rows. Lane l owns output col l:
// W[l][0..127] cached in 128 VGPRs (staged via LDS for coalescing), h row
// elements broadcast across the wave with v_readlane -> pure-VALU inner loop.
__global__ __launch_bounds__(256) void k_pass_a(
    const float* __restrict__ h, const float* __restrict__ W,
    const float* __restrict__ attn, float* __restrict__ z,
    float* __restrict__ s1, float* __restrict__ s2) {
  __shared__ float Wl[64 * 129];  // pad 129: lane-major reads conflict-free
  const int tid = threadIdx.x;
#pragma unroll
  for (int j = 0; j < 8; ++j) {
    int i4 = tid + j * 256;  // 2048 float4s total
    const float4 v = reinterpret_cast<const float4*>(W)[i4];
    int i = i4 * 4;
    int col = i >> 7, k = i & 127;
    float* p = &Wl[col * 129 + k];
    p[0] = v.x; p[1] = v.y; p[2] = v.z; p[3] = v.w;
  }
  __syncthreads();
  const int lane = tid & 63;
  const int wid = tid >> 6;
  float Wreg[128];
#pragma unroll
  for (int k = 0; k < 128; ++k) Wreg[k] = Wl[lane * 129 + k];
  const float w1v = attn[lane];
  const float w2v = attn[64 + lane];
  const int base = blockIdx.x * 64 + wid * 16;
  for (int i = 0; i < 16; ++i) {
    int r = base + i;
    if (r >= NN) return;  // wave-uniform
    const float* hr = h + (size_t)r * IND;
    float h0 = hr[lane];
    float h1 = hr[64 + lane];
    float acc = 0.f;
#pragma unroll
    for (int k = 0; k < 64; ++k)
      acc = fmaf(__uint_as_float(__builtin_amdgcn_readlane(__float_as_uint(h0), k)),
                 Wreg[k], acc);
#pragma unroll
    for (int k = 0; k < 64; ++k)
      acc = fmaf(__uint_as_float(__builtin_amdgcn_readlane(__float_as_uint(h1), k)),
                 Wreg[64 + k], acc);
    z[(size_t)r * OUTD + lane] = acc;
    float p = acc * w1v, q = acc * w2v;
#pragma unroll
    for (int m = 32; m >= 1; m >>= 1) {
      p += __shfl_xor(p, m, 64);
      q += __shfl_xor(q, m, 64);
    }
    if (lane == 0) { s1[r] = p; s2[r] = q; }
  }
}

// ---------------- Pass B: ee[e] = exp(leaky(s1[src]+s2[dst]+r_h.w3)), denom += ee
// 16 lanes per edge; r_h tile read fully coalesced as float4.
__global__ __launch_bounds__(256) void k_pass_b(
    const float* __restrict__ r_h, const float* __restrict__ attn,
    const int* __restrict__ esrc, const int* __restrict__ edst,
    const float* __restrict__ s1, const float* __restrict__ s2,
    float* __restrict__ ee, float* __restrict__ denom) {
  const int t = blockIdx.x * 256 + threadIdx.x;
  const int e = t >> 4;
  const int sub = t & 15;
  float4 rv = reinterpret_cast<const float4*>(r_h)[e * 16 + sub];
  float4 wv = reinterpret_cast<const float4*>(attn + 2 * OUTD)[sub];
  float d = rv.x * wv.x + rv.y * wv.y + rv.z * wv.z + rv.w * wv.w;
  d += __shfl_xor(d, 1, 64);
  d += __shfl_xor(d, 2, 64);
  d += __shfl_xor(d, 4, 64);
  d += __shfl_xor(d, 8, 64);
  if (sub == 0) {
    int s = esrc[e], dd = edst[e];
    float a = s1[s] + s2[dd] + d;
    float el = a > 0.f ? a : 0.01f * a;
    // no seg_max subtraction: |a| <= ~10 so exp() is safe in f32 and the
    // resulting alpha is mathematically identical to the reference's.
    float ex = __expf(el);
    ee[e] = ex;
    atomicAdd(&denom[dd], ex);
  }
}

// ---------------- Pass C: out[dst][:] += (ee/denom[dst]) * z[src][:] -------
// One wave per edge; lane = output channel. z rows are L2/L3-resident.
__global__ __launch_bounds__(256) void k_pass_c(
    const float* __restrict__ z, const int* __restrict__ esrc,
    const int* __restrict__ edst, const float* __restrict__ ee,
    const float* __restrict__ denom, float* __restrict__ out) {
  const int wid = threadIdx.x >> 6, lane = threadIdx.x & 63;
  const int e = blockIdx.x * 4 + wid;
  if (e >= EE) return;
  int s = esrc[e], d = edst[e];
  float alpha = ee[e] / denom[d];
  float v = alpha * z[(size_t)s * OUTD + lane];
  atomicAdd(&out[(size_t)d * OUTD + lane], v);
}

// ---------------- Pass D: out = (denom>0) ? relu(agg + z@LW) : 0 -----------
// Same readlane-matmul trick; LW[k][lane] cached per lane (64 VGPRs), loads
// are coalesced and L1-resident. In-place on d_out (agg came from pass C).
__global__ __launch_bounds__(256) void k_pass_d(
    const float* __restrict__ z, const float* __restrict__ LW,
    const float* __restrict__ denom, float* __restrict__ out) {
  const int lane = threadIdx.x & 63, wid = threadIdx.x >> 6;
  float LWreg[64];
#pragma unroll
  for (int k = 0; k < 64; ++k) LWreg[k] = LW[k * OUTD + lane];
  const int base = blockIdx.x * 64 + wid * 16;
  for (int i = 0; i < 16; ++i) {
    int r = base + i;
    if (r >= NN) return;  // wave-uniform
    float zv = z[(size_t)r * OUTD + lane];
    float acc = out[(size_t)r * OUTD + lane];  // agg
#pragma unroll
    for (int k = 0; k < 64; ++k)
      acc = fmaf(__uint_as_float(__builtin_amdgcn_readlane(__float_as_uint(zv), k)),
                 LWreg[k], acc);
    float res = (denom[r] > 0.f) ? (acc > 0.f ? acc : 0.f) : 0.f;
    out[(size_t)r * OUTD + lane] = res;
  }
}

extern "C" void kernel_launch(void* const* d_in, const int* in_sizes, int n_in,
                              void* d_out, int out_size, void* d_ws, size_t ws_size,
                              hipStream_t stream) {
  const float* h    = (const float*)d_in[0];  // [N,128]
  const float* r_h  = (const float*)d_in[1];  // [E,64]
  const float* W_fc = (const float*)d_in[2];  // [64,128]
  const float* attn = (const float*)d_in[3];  // [1,192]
  const float* LW   = (const float*)d_in[4];  // [64,64]
  const int* esrc   = (const int*)d_in[5];    // [E]
  const int* edst   = (const int*)d_in[6];    // [E]
  float* out = (float*)d_out;                 // [N,64]

  char* ws = (char*)d_ws;
  float* z     = (float*)(ws);                       // N*64*4 = 12,800,000 B
  float* s1    = (float*)(ws + 12800000);            // N*4    =    200,000 B
  float* s2    = (float*)(ws + 13000000);            // N*4    =    200,000 B
  float* ee    = (float*)(ws + 13200000);            // E*4    =  3,200,000 B
  float* denom = (float*)(ws + 16400000);            // N*4    =    200,000 B
  // total ws use: 16.6 MB

  hipMemsetAsync(out, 0, (size_t)NN * OUTD * sizeof(float), stream);
  hipMemsetAsync(denom, 0, (size_t)NN * sizeof(float), stream);

  k_pass_a<<<(NN + 63) / 64, 256, 0, stream>>>(h, W_fc, attn, z, s1, s2);
  k_pass_b<<<EE * 16 / 256, 256, 0, stream>>>(r_h, attn, esrc, edst, s1, s2, ee, denom);
  k_pass_c<<<EE / 4, 256, 0, stream>>>(z, esrc, edst, ee, denom, out);
  k_pass_d<<<(NN + 63) / 64, 256, 0, stream>>>(z, LW, denom, out);
}

// Round 2
// 473.614 us; speedup vs baseline: 1.1784x; 1.1784x over previous
//
#include <hip/hip_runtime.h>

#define NN 50000
#define EE 800000
#define IND 128
#define OUTD 64
#define NB 49  // ceil(NN/1024) scan blocks

// ---------------- Pass A: z = h @ W^T, s1 = z.w1, s2 = z.w2 ----------------
// Lane l owns output col l: W[l][:] in 128 VGPRs (staged via LDS), h row
// broadcast with v_readlane -> pure-VALU inner loop.
__global__ __launch_bounds__(256) void k_pass_a(
    const float* __restrict__ h, const float* __restrict__ W,
    const float* __restrict__ attn, float* __restrict__ z,
    float* __restrict__ s1, float* __restrict__ s2) {
  __shared__ float Wl[64 * 129];
  const int tid = threadIdx.x;
#pragma unroll
  for (int j = 0; j < 8; ++j) {
    int i4 = tid + j * 256;
    const float4 v = reinterpret_cast<const float4*>(W)[i4];
    int i = i4 * 4;
    int col = i >> 7, k = i & 127;
    float* p = &Wl[col * 129 + k];
    p[0] = v.x; p[1] = v.y; p[2] = v.z; p[3] = v.w;
  }
  __syncthreads();
  const int lane = tid & 63;
  const int wid = tid >> 6;
  float Wreg[128];
#pragma unroll
  for (int k = 0; k < 128; ++k) Wreg[k] = Wl[lane * 129 + k];
  const float w1v = attn[lane];
  const float w2v = attn[64 + lane];
  const int base = blockIdx.x * 64 + wid * 16;
  for (int i = 0; i < 16; ++i) {
    int r = base + i;
    if (r >= NN) return;  // wave-uniform
    const float* hr = h + (size_t)r * IND;
    float h0 = hr[lane];
    float h1 = hr[64 + lane];
    float acc = 0.f;
#pragma unroll
    for (int k = 0; k < 64; ++k)
      acc = fmaf(__uint_as_float(__builtin_amdgcn_readlane(__float_as_uint(h0), k)),
                 Wreg[k], acc);
#pragma unroll
    for (int k = 0; k < 64; ++k)
      acc = fmaf(__uint_as_float(__builtin_amdgcn_readlane(__float_as_uint(h1), k)),
                 Wreg[64 + k], acc);
    z[(size_t)r * OUTD + lane] = acc;
    float p = acc * w1v, q = acc * w2v;
#pragma unroll
    for (int m = 32; m >= 1; m >>= 1) {
      p += __shfl_xor(p, m, 64);
      q += __shfl_xor(q, m, 64);
    }
    if (lane == 0) { s1[r] = p; s2[r] = q; }
  }
}

// ---------------- Pass B: ee[e] = exp(leaky(s1[src]+s2[dst]+r_h.w3)); deg[dst]++
// 16 lanes per edge; r_h streamed fully coalesced (index e*16+sub == t).
// No seg_max subtraction: |a| small, exp safe in f32; alpha identical.
__global__ __launch_bounds__(256) void k_pass_b(
    const float* __restrict__ r_h, const float* __restrict__ attn,
    const int* __restrict__ esrc, const int* __restrict__ edst,
    const float* __restrict__ s1, const float* __restrict__ s2,
    float* __restrict__ ee, int* __restrict__ deg) {
  const int t = blockIdx.x * 256 + threadIdx.x;
  const int sub = t & 15;
  float4 rv = reinterpret_cast<const float4*>(r_h)[t];
  float4 wv = reinterpret_cast<const float4*>(attn + 2 * OUTD)[sub];
  float d = rv.x * wv.x + rv.y * wv.y + rv.z * wv.z + rv.w * wv.w;
  d += __shfl_xor(d, 1, 64);
  d += __shfl_xor(d, 2, 64);
  d += __shfl_xor(d, 4, 64);
  d += __shfl_xor(d, 8, 64);
  if (sub == 0) {
    const int e = t >> 4;
    int s = esrc[e], dd = edst[e];
    float a = s1[s] + s2[dd] + d;
    float el = a > 0.f ? a : 0.01f * a;
    ee[e] = __expf(el);
    atomicAdd(&deg[dd], 1);
  }
}

// ---------------- Scan: exclusive prefix over deg (CSR offsets) ------------
__global__ __launch_bounds__(1024) void k_scan1(
    const int* __restrict__ deg, int* __restrict__ offL,
    int* __restrict__ blocksum) {
  __shared__ int wsum[16];
  __shared__ int woff[17];
  const int tid = threadIdx.x;
  const int gid = blockIdx.x * 1024 + tid;
  const int lane = tid & 63, wid = tid >> 6;
  int v = (gid < NN) ? deg[gid] : 0;
  int incl = v;
#pragma unroll
  for (int o = 1; o < 64; o <<= 1) {
    int t = __shfl_up(incl, o, 64);
    if (lane >= o) incl += t;
  }
  if (lane == 63) wsum[wid] = incl;
  __syncthreads();
  if (wid == 0 && lane < 16) {
    int s = wsum[lane];
    int si = s;
#pragma unroll
    for (int o = 1; o < 16; o <<= 1) {
      int t = __shfl_up(si, o, 64);
      if (lane >= o) si += t;
    }
    woff[lane] = si - s;  // exclusive wave offset
    if (lane == 15) woff[16] = si;  // block total
  }
  __syncthreads();
  if (gid < NN) offL[gid] = woff[wid] + incl - v;
  if (tid == 0) blocksum[blockIdx.x] = woff[16];
}

__global__ __launch_bounds__(64) void k_scan2(
    const int* __restrict__ blocksum, int* __restrict__ blockoff) {
  const int lane = threadIdx.x;
  int v = (lane < NB) ? blocksum[lane] : 0;
  int incl = v;
#pragma unroll
  for (int o = 1; o < 64; o <<= 1) {
    int t = __shfl_up(incl, o, 64);
    if (lane >= o) incl += t;
  }
  if (lane < NB) blockoff[lane] = incl - v;
}

// ---------------- Scatter: bucket (src, ee) pairs by dst -------------------
__global__ __launch_bounds__(256) void k_scatter(
    const int* __restrict__ esrc, const int* __restrict__ edst,
    const float* __restrict__ ee, const int* __restrict__ offL,
    const int* __restrict__ blockoff, int* __restrict__ cursor,
    int2* __restrict__ pairs) {
  const int e = blockIdx.x * 256 + threadIdx.x;
  if (e >= EE) return;
  int d = edst[e];
  int pos = blockoff[d >> 10] + offL[d] + atomicAdd(&cursor[d], 1);
  pairs[pos] = make_int2(esrc[e], __float_as_int(ee[e]));
}

// ---------------- Agg (fused C+D): gather per dst node ---------------------
// One wave per node; lane = channel. acc = sum(w * z[src]), wsum = sum(w);
// out = relu(acc/wsum + z[r]@LW) if deg>0 else 0. Single write per row.
__global__ __launch_bounds__(256) void k_agg(
    const float* __restrict__ z, const int2* __restrict__ pairs,
    const int* __restrict__ offL, const int* __restrict__ blockoff,
    const int* __restrict__ deg, const float* __restrict__ LW,
    float* __restrict__ out) {
  const int lane = threadIdx.x & 63, wid = threadIdx.x >> 6;
  float LWreg[64];
#pragma unroll
  for (int k = 0; k < 64; ++k) LWreg[k] = LW[k * OUTD + lane];
  const int r = blockIdx.x * 4 + wid;
  if (r >= NN) return;
  const int cnt = deg[r];
  const int2* pp = pairs + (blockoff[r >> 10] + offL[r]);
  float acc = 0.f, wsum = 0.f;
  int i = 0;
  for (; i + 4 <= cnt; i += 4) {
    int2 p0 = pp[i], p1 = pp[i + 1], p2 = pp[i + 2], p3 = pp[i + 3];
    float a0 = z[(size_t)p0.x * OUTD + lane];
    float a1 = z[(size_t)p1.x * OUTD + lane];
    float a2 = z[(size_t)p2.x * OUTD + lane];
    float a3 = z[(size_t)p3.x * OUTD + lane];
    float w0 = __int_as_float(p0.y), w1 = __int_as_float(p1.y);
    float w2 = __int_as_float(p2.y), w3 = __int_as_float(p3.y);
    acc = fmaf(w0, a0, acc);
    acc = fmaf(w1, a1, acc);
    acc = fmaf(w2, a2, acc);
    acc = fmaf(w3, a3, acc);
    wsum += (w0 + w1) + (w2 + w3);
  }
  for (; i < cnt; ++i) {
    int2 p = pp[i];
    float w = __int_as_float(p.y);
    acc = fmaf(w, z[(size_t)p.x * OUTD + lane], acc);
    wsum += w;
  }
  float zv = z[(size_t)r * OUTD + lane];
  float lacc = 0.f;
#pragma unroll
  for (int k = 0; k < 64; ++k)
    lacc = fmaf(__uint_as_float(__builtin_amdgcn_readlane(__float_as_uint(zv), k)),
                LWreg[k], lacc);
  float res = 0.f;
  if (cnt > 0) {
    float v = acc / wsum + lacc;
    res = v > 0.f ? v : 0.f;
  }
  out[(size_t)r * OUTD + lane] = res;
}

extern "C" void kernel_launch(void* const* d_in, const int* in_sizes, int n_in,
                              void* d_out, int out_size, void* d_ws, size_t ws_size,
                              hipStream_t stream) {
  const float* h    = (const float*)d_in[0];  // [N,128]
  const float* r_h  = (const float*)d_in[1];  // [E,64]
  const float* W_fc = (const float*)d_in[2];  // [64,128]
  const float* attn = (const float*)d_in[3];  // [1,192]
  const float* LW   = (const float*)d_in[4];  // [64,64]
  const int* esrc   = (const int*)d_in[5];    // [E]
  const int* edst   = (const int*)d_in[6];    // [E]
  float* out = (float*)d_out;                 // [N,64]

  char* ws = (char*)d_ws;
  float* z      = (float*)(ws);               // 12,800,000 B
  float* ee     = (float*)(ws + 12800000);    //  3,200,000 B
  int2*  pairs  = (int2*)(ws + 16000000);     //  6,400,000 B
  float* s1     = (float*)(ws + 22400000);    //    200,000 B
  float* s2     = (float*)(ws + 22600000);    //    200,000 B
  int*   deg    = (int*)(ws + 22800000);      //    200,000 B
  int*   cursor = (int*)(ws + 23000000);      //    200,000 B
  int*   offL   = (int*)(ws + 23200000);      //    200,000 B
  int*   bsum   = (int*)(ws + 23400000);      //        256 B
  int*   boff   = (int*)(ws + 23401024);      //        256 B
  // total ws use ~23.5 MB

  hipMemsetAsync(deg, 0, (size_t)NN * sizeof(int), stream);
  hipMemsetAsync(cursor, 0, (size_t)NN * sizeof(int), stream);

  k_pass_a<<<(NN + 63) / 64, 256, 0, stream>>>(h, W_fc, attn, z, s1, s2);
  k_pass_b<<<EE * 16 / 256, 256, 0, stream>>>(r_h, attn, esrc, edst, s1, s2, ee, deg);
  k_scan1<<<NB, 1024, 0, stream>>>(deg, offL, bsum);
  k_scan2<<<1, 64, 0, stream>>>(bsum, boff);
  k_scatter<<<(EE + 255) / 256, 256, 0, stream>>>(esrc, edst, ee, offL, boff, cursor, pairs);
  k_agg<<<(NN + 3) / 4, 256, 0, stream>>>(z, pairs, offL, boff, deg, LW, out);
}

// Round 3
// 461.015 us; speedup vs baseline: 1.2106x; 1.0273x over previous
//
#include <hip/hip_runtime.h>

#define NN 50000
#define EE 800000
#define IND 128
#define OUTD 64
#define NB 49  // ceil(NN/1024) scan blocks

// ---------------- Deg+rank: rank[e] = slot of e within its dst bucket ------
__global__ __launch_bounds__(256) void k_deg(
    const int* __restrict__ edst, int* __restrict__ deg, int* __restrict__ rank) {
  const int e = blockIdx.x * 256 + threadIdx.x;
  if (e < EE) rank[e] = atomicAdd(&deg[edst[e]], 1);
}

// ---------------- Pass A: z = h @ W^T, s1 = z.w1, s2 = z.w2 ----------------
// Lane l owns output col l: W[l][:] in 128 VGPRs (staged via LDS), h row
// broadcast with v_readlane -> pure-VALU inner loop.
__global__ __launch_bounds__(256) void k_pass_a(
    const float* __restrict__ h, const float* __restrict__ W,
    const float* __restrict__ attn, float* __restrict__ z,
    float* __restrict__ s1, float* __restrict__ s2) {
  __shared__ float Wl[64 * 129];
  const int tid = threadIdx.x;
#pragma unroll
  for (int j = 0; j < 8; ++j) {
    int i4 = tid + j * 256;
    const float4 v = reinterpret_cast<const float4*>(W)[i4];
    int i = i4 * 4;
    int col = i >> 7, k = i & 127;
    float* p = &Wl[col * 129 + k];
    p[0] = v.x; p[1] = v.y; p[2] = v.z; p[3] = v.w;
  }
  __syncthreads();
  const int lane = tid & 63;
  const int wid = tid >> 6;
  float Wreg[128];
#pragma unroll
  for (int k = 0; k < 128; ++k) Wreg[k] = Wl[lane * 129 + k];
  const float w1v = attn[lane];
  const float w2v = attn[64 + lane];
  const int base = blockIdx.x * 64 + wid * 16;
  for (int i = 0; i < 16; ++i) {
    int r = base + i;
    if (r >= NN) return;  // wave-uniform
    const float* hr = h + (size_t)r * IND;
    float h0 = hr[lane];
    float h1 = hr[64 + lane];
    float acc = 0.f;
#pragma unroll
    for (int k = 0; k < 64; ++k)
      acc = fmaf(__uint_as_float(__builtin_amdgcn_readlane(__float_as_uint(h0), k)),
                 Wreg[k], acc);
#pragma unroll
    for (int k = 0; k < 64; ++k)
      acc = fmaf(__uint_as_float(__builtin_amdgcn_readlane(__float_as_uint(h1), k)),
                 Wreg[64 + k], acc);
    z[(size_t)r * OUTD + lane] = acc;
    float p = acc * w1v, q = acc * w2v;
#pragma unroll
    for (int m = 32; m >= 1; m >>= 1) {
      p += __shfl_xor(p, m, 64);
      q += __shfl_xor(q, m, 64);
    }
    if (lane == 0) { s1[r] = p; s2[r] = q; }
  }
}

// ---------------- Scan: exclusive prefix over deg (CSR offsets) ------------
__global__ __launch_bounds__(1024) void k_scan1(
    const int* __restrict__ deg, int* __restrict__ offL,
    int* __restrict__ blocksum) {
  __shared__ int wsum[16];
  __shared__ int woff[17];
  const int tid = threadIdx.x;
  const int gid = blockIdx.x * 1024 + tid;
  const int lane = tid & 63, wid = tid >> 6;
  int v = (gid < NN) ? deg[gid] : 0;
  int incl = v;
#pragma unroll
  for (int o = 1; o < 64; o <<= 1) {
    int t = __shfl_up(incl, o, 64);
    if (lane >= o) incl += t;
  }
  if (lane == 63) wsum[wid] = incl;
  __syncthreads();
  if (wid == 0 && lane < 16) {
    int s = wsum[lane];
    int si = s;
#pragma unroll
    for (int o = 1; o < 16; o <<= 1) {
      int t = __shfl_up(si, o, 64);
      if (lane >= o) si += t;
    }
    woff[lane] = si - s;
    if (lane == 15) woff[16] = si;
  }
  __syncthreads();
  if (gid < NN) offL[gid] = woff[wid] + incl - v;
  if (tid == 0) blocksum[blockIdx.x] = woff[16];
}

__global__ __launch_bounds__(64) void k_scan2(
    const int* __restrict__ blocksum, int* __restrict__ blockoff) {
  const int lane = threadIdx.x;
  int v = (lane < NB) ? blocksum[lane] : 0;
  int incl = v;
#pragma unroll
  for (int o = 1; o < 64; o <<= 1) {
    int t = __shfl_up(incl, o, 64);
    if (lane >= o) incl += t;
  }
  if (lane < NB) blockoff[lane] = incl - v;
}

// ---------------- Attn + scatter (fused): 16 lanes per edge ----------------
// d = r_h[e].w3 (coalesced float4 stream); ee = exp(leaky(s1+s2+d));
// pairs[off[dst]+rank[e]] = (src, ee). No atomics; ee never hits HBM.
// No seg_max subtraction: |a| small, exp safe in f32; alpha identical.
__global__ __launch_bounds__(256) void k_attn_scatter(
    const float* __restrict__ r_h, const float* __restrict__ attn,
    const int* __restrict__ esrc, const int* __restrict__ edst,
    const float* __restrict__ s1, const float* __restrict__ s2,
    const int* __restrict__ rank, const int* __restrict__ offL,
    const int* __restrict__ blockoff, int2* __restrict__ pairs) {
  const int t = blockIdx.x * 256 + threadIdx.x;
  const int sub = t & 15;
  float4 rv = reinterpret_cast<const float4*>(r_h)[t];
  float4 wv = reinterpret_cast<const float4*>(attn + 2 * OUTD)[sub];
  float d = rv.x * wv.x + rv.y * wv.y + rv.z * wv.z + rv.w * wv.w;
  d += __shfl_xor(d, 1, 64);
  d += __shfl_xor(d, 2, 64);
  d += __shfl_xor(d, 4, 64);
  d += __shfl_xor(d, 8, 64);
  if (sub == 0) {
    const int e = t >> 4;
    int s = esrc[e], dd = edst[e];
    float a = s1[s] + s2[dd] + d;
    float el = a > 0.f ? a : 0.01f * a;
    float ex = __expf(el);
    int pos = blockoff[dd >> 10] + offL[dd] + rank[e];
    pairs[pos] = make_int2(s, __float_as_int(ex));
  }
}

// ---------------- Agg (fused C+D): gather per dst node ---------------------
// One wave per node. lane = (slot = lane>>4, sub = lane&15): slot indexes 4
// concurrent edges, sub indexes the channel-quad (float4). Each z row is
// fetched as 16 x float4 (full 256B row); 8 edges in flight per iteration.
// Loop-weight epilogue split across slots (16 k each), slot-reduced together
// with acc via shfl_xor(16/32). Single float4 row write.
__global__ __launch_bounds__(256) void k_agg(
    const float* __restrict__ z, const int2* __restrict__ pairs,
    const int* __restrict__ offL, const int* __restrict__ blockoff,
    const int* __restrict__ deg, const float* __restrict__ LW,
    float* __restrict__ out) {
  const int lane = threadIdx.x & 63, wid = threadIdx.x >> 6;
  const int slot = lane >> 4, sub = lane & 15;
  // LWreg[kl] = LW[slot*16+kl][4*sub .. 4*sub+3]
  float4 LWreg[16];
#pragma unroll
  for (int kl = 0; kl < 16; ++kl)
    LWreg[kl] = reinterpret_cast<const float4*>(LW)[(slot * 16 + kl) * 16 + sub];
  const int r = blockIdx.x * 4 + wid;  // grid exact: 12500*4 = 50000
  const int cnt = deg[r];
  const int2* pp = pairs + (blockoff[r >> 10] + offL[r]);
  float4 acc = make_float4(0.f, 0.f, 0.f, 0.f);
  float wsum = 0.f;
  for (int i = 0; i < cnt; i += 8) {
    int e0 = i + slot, e1 = i + 4 + slot;
    bool v0 = e0 < cnt, v1 = e1 < cnt;
    int2 p0 = pp[v0 ? e0 : 0];
    int2 p1 = pp[v1 ? e1 : 0];
    float4 z0 = reinterpret_cast<const float4*>(z)[(size_t)p0.x * 16 + sub];
    float4 z1 = reinterpret_cast<const float4*>(z)[(size_t)p1.x * 16 + sub];
    float w0 = v0 ? __int_as_float(p0.y) : 0.f;
    float w1 = v1 ? __int_as_float(p1.y) : 0.f;
    acc.x = fmaf(w0, z0.x, acc.x);
    acc.y = fmaf(w0, z0.y, acc.y);
    acc.z = fmaf(w0, z0.z, acc.z);
    acc.w = fmaf(w0, z0.w, acc.w);
    acc.x = fmaf(w1, z1.x, acc.x);
    acc.y = fmaf(w1, z1.y, acc.y);
    acc.z = fmaf(w1, z1.z, acc.z);
    acc.w = fmaf(w1, z1.w, acc.w);
    wsum += w0 + w1;
  }
  // loop-weight partial: k in [slot*16, slot*16+16)
  float4 lacc = make_float4(0.f, 0.f, 0.f, 0.f);
#pragma unroll
  for (int j = 0; j < 4; ++j) {
    float4 zq = reinterpret_cast<const float4*>(z)[(size_t)r * 16 + slot * 4 + j];
    float zk[4] = {zq.x, zq.y, zq.z, zq.w};
#pragma unroll
    for (int c = 0; c < 4; ++c) {
      float4 lw = LWreg[4 * j + c];
      lacc.x = fmaf(zk[c], lw.x, lacc.x);
      lacc.y = fmaf(zk[c], lw.y, lacc.y);
      lacc.z = fmaf(zk[c], lw.z, lacc.z);
      lacc.w = fmaf(zk[c], lw.w, lacc.w);
    }
  }
  // reduce wsum across slots (sub preserved)
  wsum += __shfl_xor(wsum, 16, 64);
  wsum += __shfl_xor(wsum, 32, 64);
  float inv = (cnt > 0) ? 1.f / wsum : 0.f;
  float4 t;
  t.x = fmaf(acc.x, inv, lacc.x);
  t.y = fmaf(acc.y, inv, lacc.y);
  t.z = fmaf(acc.z, inv, lacc.z);
  t.w = fmaf(acc.w, inv, lacc.w);
  t.x += __shfl_xor(t.x, 16, 64); t.x += __shfl_xor(t.x, 32, 64);
  t.y += __shfl_xor(t.y, 16, 64); t.y += __shfl_xor(t.y, 32, 64);
  t.z += __shfl_xor(t.z, 16, 64); t.z += __shfl_xor(t.z, 32, 64);
  t.w += __shfl_xor(t.w, 16, 64); t.w += __shfl_xor(t.w, 32, 64);
  if (slot == 0) {
    float4 res;
    res.x = (cnt > 0 && t.x > 0.f) ? t.x : 0.f;
    res.y = (cnt > 0 && t.y > 0.f) ? t.y : 0.f;
    res.z = (cnt > 0 && t.z > 0.f) ? t.z : 0.f;
    res.w = (cnt > 0 && t.w > 0.f) ? t.w : 0.f;
    reinterpret_cast<float4*>(out)[(size_t)r * 16 + sub] = res;
  }
}

extern "C" void kernel_launch(void* const* d_in, const int* in_sizes, int n_in,
                              void* d_out, int out_size, void* d_ws, size_t ws_size,
                              hipStream_t stream) {
  const float* h    = (const float*)d_in[0];  // [N,128]
  const float* r_h  = (const float*)d_in[1];  // [E,64]
  const float* W_fc = (const float*)d_in[2];  // [64,128]
  const float* attn = (const float*)d_in[3];  // [1,192]
  const float* LW   = (const float*)d_in[4];  // [64,64]
  const int* esrc   = (const int*)d_in[5];    // [E]
  const int* edst   = (const int*)d_in[6];    // [E]
  float* out = (float*)d_out;                 // [N,64]

  char* ws = (char*)d_ws;
  float* z     = (float*)(ws);                // 12,800,000 B
  int2*  pairs = (int2*)(ws + 12800000);      //  6,400,000 B
  int*   rank  = (int*)(ws + 19200000);       //  3,200,000 B
  float* s1    = (float*)(ws + 22400000);     //    200,000 B
  float* s2    = (float*)(ws + 22600000);     //    200,000 B
  int*   deg   = (int*)(ws + 22800000);       //    200,000 B
  int*   offL  = (int*)(ws + 23000000);       //    200,000 B
  int*   bsum  = (int*)(ws + 23200000);       //        256 B
  int*   boff  = (int*)(ws + 23201024);       //        256 B
  // total ws use ~23.3 MB

  hipMemsetAsync(deg, 0, (size_t)NN * sizeof(int), stream);

  k_deg<<<(EE + 255) / 256, 256, 0, stream>>>(edst, deg, rank);
  k_pass_a<<<(NN + 63) / 64, 256, 0, stream>>>(h, W_fc, attn, z, s1, s2);
  k_scan1<<<NB, 1024, 0, stream>>>(deg, offL, bsum);
  k_scan2<<<1, 64, 0, stream>>>(bsum, boff);
  k_attn_scatter<<<EE * 16 / 256, 256, 0, stream>>>(
      r_h, attn, esrc, edst, s1, s2, rank, offL, boff, pairs);
  k_agg<<<NN / 4, 256, 0, stream>>>(z, pairs, offL, boff, deg, LW, out);
}

// Round 4
// 431.165 us; speedup vs baseline: 1.2944x; 1.0692x over previous
//
#include <hip/hip_runtime.h>
#include <hip/hip_bf16.h>

#define NN 50000
#define EE 800000
#define IND 128
#define OUTD 64
#define NB 49        // ceil(NN/1024) scan blocks
#define PA_BLOCKS 782   // ceil(NN/64)
#define DEG_BLOCKS 391  // ceil(EE/2048)

// ---------------- Front (fused): deg/rank count + z = h@W^T, s1, s2 --------
// Blocks [0,782): GEMM part — lane l owns output col l, W[l][:] in 128 VGPRs,
// h row broadcast via v_readlane (pure-VALU inner loop). Writes z (f32) and
// zb (bf16, for the gather path in k_agg).
// Blocks [782,1173): deg part — rank[e] = atomicAdd(&deg[edst[e]],1).
// Fusing lets the deg atomics (head of the CSR critical path) overlap the GEMM.
__global__ __launch_bounds__(256) void k_front(
    const float* __restrict__ h, const float* __restrict__ W,
    const float* __restrict__ attn, const int* __restrict__ edst,
    float* __restrict__ z, __hip_bfloat16* __restrict__ zb,
    float* __restrict__ s1, float* __restrict__ s2,
    int* __restrict__ deg, int* __restrict__ rank) {
  if (blockIdx.x >= PA_BLOCKS) {  // ---- deg part
    const int base = (blockIdx.x - PA_BLOCKS) * 2048 + threadIdx.x;
#pragma unroll
    for (int j = 0; j < 8; ++j) {
      int e = base + j * 256;
      if (e < EE) rank[e] = atomicAdd(&deg[edst[e]], 1);
    }
    return;
  }
  // ---- GEMM part
  __shared__ float Wl[64 * 129];
  const int tid = threadIdx.x;
#pragma unroll
  for (int j = 0; j < 8; ++j) {
    int i4 = tid + j * 256;
    const float4 v = reinterpret_cast<const float4*>(W)[i4];
    int i = i4 * 4;
    int col = i >> 7, k = i & 127;
    float* p = &Wl[col * 129 + k];
    p[0] = v.x; p[1] = v.y; p[2] = v.z; p[3] = v.w;
  }
  __syncthreads();
  const int lane = tid & 63;
  const int wid = tid >> 6;
  float Wreg[128];
#pragma unroll
  for (int k = 0; k < 128; ++k) Wreg[k] = Wl[lane * 129 + k];
  const float w1v = attn[lane];
  const float w2v = attn[64 + lane];
  const int base = blockIdx.x * 64 + wid * 16;
  for (int i = 0; i < 16; ++i) {
    int r = base + i;
    if (r >= NN) return;  // wave-uniform
    const float* hr = h + (size_t)r * IND;
    float h0 = hr[lane];
    float h1 = hr[64 + lane];
    float acc = 0.f;
#pragma unroll
    for (int k = 0; k < 64; ++k)
      acc = fmaf(__uint_as_float(__builtin_amdgcn_readlane(__float_as_uint(h0), k)),
                 Wreg[k], acc);
#pragma unroll
    for (int k = 0; k < 64; ++k)
      acc = fmaf(__uint_as_float(__builtin_amdgcn_readlane(__float_as_uint(h1), k)),
                 Wreg[64 + k], acc);
    z[(size_t)r * OUTD + lane] = acc;
    zb[(size_t)r * OUTD + lane] = __float2bfloat16(acc);
    float p = acc * w1v, q = acc * w2v;
#pragma unroll
    for (int m = 32; m >= 1; m >>= 1) {
      p += __shfl_xor(p, m, 64);
      q += __shfl_xor(q, m, 64);
    }
    if (lane == 0) { s1[r] = p; s2[r] = q; }
  }
}

// ---------------- Scan: exclusive prefix over deg (CSR offsets) ------------
__global__ __launch_bounds__(1024) void k_scan1(
    const int* __restrict__ deg, int* __restrict__ offL,
    int* __restrict__ blocksum) {
  __shared__ int wsum[16];
  __shared__ int woff[17];
  const int tid = threadIdx.x;
  const int gid = blockIdx.x * 1024 + tid;
  const int lane = tid & 63, wid = tid >> 6;
  int v = (gid < NN) ? deg[gid] : 0;
  int incl = v;
#pragma unroll
  for (int o = 1; o < 64; o <<= 1) {
    int t = __shfl_up(incl, o, 64);
    if (lane >= o) incl += t;
  }
  if (lane == 63) wsum[wid] = incl;
  __syncthreads();
  if (wid == 0 && lane < 16) {
    int s = wsum[lane];
    int si = s;
#pragma unroll
    for (int o = 1; o < 16; o <<= 1) {
      int t = __shfl_up(si, o, 64);
      if (lane >= o) si += t;
    }
    woff[lane] = si - s;
    if (lane == 15) woff[16] = si;
  }
  __syncthreads();
  if (gid < NN) offL[gid] = woff[wid] + incl - v;
  if (tid == 0) blocksum[blockIdx.x] = woff[16];
}

__global__ __launch_bounds__(64) void k_scan2(
    const int* __restrict__ blocksum, int* __restrict__ blockoff) {
  const int lane = threadIdx.x;
  int v = (lane < NB) ? blocksum[lane] : 0;
  int incl = v;
#pragma unroll
  for (int o = 1; o < 64; o <<= 1) {
    int t = __shfl_up(incl, o, 64);
    if (lane >= o) incl += t;
  }
  if (lane < NB) blockoff[lane] = incl - v;
}

// ---------------- Attn + scatter (fused): 16 lanes per edge ----------------
// d = r_h[e].w3 (coalesced float4 stream); ee = exp(leaky(s1+s2+d));
// pairs[off[dst]+rank[e]] = (src, ee). No atomics; ee never hits HBM.
// No seg_max subtraction: |a| small, exp safe in f32; alpha identical.
__global__ __launch_bounds__(256) void k_attn_scatter(
    const float* __restrict__ r_h, const float* __restrict__ attn,
    const int* __restrict__ esrc, const int* __restrict__ edst,
    const float* __restrict__ s1, const float* __restrict__ s2,
    const int* __restrict__ rank, const int* __restrict__ offL,
    const int* __restrict__ blockoff, int2* __restrict__ pairs) {
  const int t = blockIdx.x * 256 + threadIdx.x;
  const int sub = t & 15;
  float4 rv = reinterpret_cast<const float4*>(r_h)[t];
  float4 wv = reinterpret_cast<const float4*>(attn + 2 * OUTD)[sub];
  float d = rv.x * wv.x + rv.y * wv.y + rv.z * wv.z + rv.w * wv.w;
  d += __shfl_xor(d, 1, 64);
  d += __shfl_xor(d, 2, 64);
  d += __shfl_xor(d, 4, 64);
  d += __shfl_xor(d, 8, 64);
  if (sub == 0) {
    const int e = t >> 4;
    int s = esrc[e], dd = edst[e];
    float a = s1[s] + s2[dd] + d;
    float el = a > 0.f ? a : 0.01f * a;
    float ex = __expf(el);
    int pos = blockoff[dd >> 10] + offL[dd] + rank[e];
    pairs[pos] = make_int2(s, __float_as_int(ex));
  }
}

// ---------------- Agg (fused): gather per dst node -------------------------
// One wave per node. lane = (slot = lane>>4, sub = lane&15): slot indexes
// edges, sub the channel-quad. Gathers use bf16 zb rows (128 B, half the
// traffic of f32); 16 edges per mega-iteration -> 8 loads in flight per lane,
// 2 latency hops per 16 edges. f32 z row used for the loop-weight epilogue.
__global__ __launch_bounds__(256) void k_agg(
    const float* __restrict__ z, const __hip_bfloat16* __restrict__ zb,
    const int2* __restrict__ pairs,
    const int* __restrict__ offL, const int* __restrict__ blockoff,
    const int* __restrict__ deg, const float* __restrict__ LW,
    float* __restrict__ out) {
  const int lane = threadIdx.x & 63, wid = threadIdx.x >> 6;
  const int slot = lane >> 4, sub = lane & 15;
  // LWreg[kl] = LW[slot*16+kl][4*sub .. 4*sub+3]
  float4 LWreg[16];
#pragma unroll
  for (int kl = 0; kl < 16; ++kl)
    LWreg[kl] = reinterpret_cast<const float4*>(LW)[(slot * 16 + kl) * 16 + sub];
  const int r = blockIdx.x * 4 + wid;  // grid exact: 12500*4 = 50000
  const int cnt = deg[r];
  const int2* pp = pairs + (blockoff[r >> 10] + offL[r]);
  float4 acc = make_float4(0.f, 0.f, 0.f, 0.f);
  float wsum = 0.f;
  for (int i = 0; i < cnt; i += 16) {
    int2 p[4];
    float w[4];
#pragma unroll
    for (int j = 0; j < 4; ++j) {
      int e = i + j * 4 + slot;
      bool v = e < cnt;
      p[j] = pp[v ? e : 0];  // pp[0] valid: loop entered => cnt >= 1
      w[j] = v ? __int_as_float(p[j].y) : 0.f;
    }
#pragma unroll
    for (int j = 0; j < 4; ++j) {
      ushort4 uz = reinterpret_cast<const ushort4*>(zb)[(size_t)p[j].x * 16 + sub];
      float zx = __uint_as_float((unsigned)uz.x << 16);
      float zy = __uint_as_float((unsigned)uz.y << 16);
      float zz = __uint_as_float((unsigned)uz.z << 16);
      float zw = __uint_as_float((unsigned)uz.w << 16);
      acc.x = fmaf(w[j], zx, acc.x);
      acc.y = fmaf(w[j], zy, acc.y);
      acc.z = fmaf(w[j], zz, acc.z);
      acc.w = fmaf(w[j], zw, acc.w);
      wsum += w[j];
    }
  }
  // loop-weight partial: k in [slot*16, slot*16+16), f32 z row
  float4 lacc = make_float4(0.f, 0.f, 0.f, 0.f);
#pragma unroll
  for (int j = 0; j < 4; ++j) {
    float4 zq = reinterpret_cast<const float4*>(z)[(size_t)r * 16 + slot * 4 + j];
    float zk[4] = {zq.x, zq.y, zq.z, zq.w};
#pragma unroll
    for (int c = 0; c < 4; ++c) {
      float4 lw = LWreg[4 * j + c];
      lacc.x = fmaf(zk[c], lw.x, lacc.x);
      lacc.y = fmaf(zk[c], lw.y, lacc.y);
      lacc.z = fmaf(zk[c], lw.z, lacc.z);
      lacc.w = fmaf(zk[c], lw.w, lacc.w);
    }
  }
  // reduce wsum across slots (sub preserved)
  wsum += __shfl_xor(wsum, 16, 64);
  wsum += __shfl_xor(wsum, 32, 64);
  float inv = (cnt > 0) ? 1.f / wsum : 0.f;
  float4 t;
  t.x = fmaf(acc.x, inv, lacc.x);
  t.y = fmaf(acc.y, inv, lacc.y);
  t.z = fmaf(acc.z, inv, lacc.z);
  t.w = fmaf(acc.w, inv, lacc.w);
  t.x += __shfl_xor(t.x, 16, 64); t.x += __shfl_xor(t.x, 32, 64);
  t.y += __shfl_xor(t.y, 16, 64); t.y += __shfl_xor(t.y, 32, 64);
  t.z += __shfl_xor(t.z, 16, 64); t.z += __shfl_xor(t.z, 32, 64);
  t.w += __shfl_xor(t.w, 16, 64); t.w += __shfl_xor(t.w, 32, 64);
  if (slot == 0) {
    float4 res;
    res.x = (cnt > 0 && t.x > 0.f) ? t.x : 0.f;
    res.y = (cnt > 0 && t.y > 0.f) ? t.y : 0.f;
    res.z = (cnt > 0 && t.z > 0.f) ? t.z : 0.f;
    res.w = (cnt > 0 && t.w > 0.f) ? t.w : 0.f;
    reinterpret_cast<float4*>(out)[(size_t)r * 16 + sub] = res;
  }
}

extern "C" void kernel_launch(void* const* d_in, const int* in_sizes, int n_in,
                              void* d_out, int out_size, void* d_ws, size_t ws_size,
                              hipStream_t stream) {
  const float* h    = (const float*)d_in[0];  // [N,128]
  const float* r_h  = (const float*)d_in[1];  // [E,64]
  const float* W_fc = (const float*)d_in[2];  // [64,128]
  const float* attn = (const float*)d_in[3];  // [1,192]
  const float* LW   = (const float*)d_in[4];  // [64,64]
  const int* esrc   = (const int*)d_in[5];    // [E]
  const int* edst   = (const int*)d_in[6];    // [E]
  float* out = (float*)d_out;                 // [N,64]

  char* ws = (char*)d_ws;
  float* z            = (float*)(ws);             // 12,800,000 B
  __hip_bfloat16* zb  = (__hip_bfloat16*)(ws + 12800000);  // 6,400,000 B
  int2*  pairs = (int2*)(ws + 19200000);          //  6,400,000 B
  int*   rank  = (int*)(ws + 25600000);           //  3,200,000 B
  float* s1    = (float*)(ws + 28800000);         //    200,000 B
  float* s2    = (float*)(ws + 29000000);         //    200,000 B
  int*   deg   = (int*)(ws + 29200000);           //    200,000 B
  int*   offL  = (int*)(ws + 29400000);           //    200,000 B
  int*   bsum  = (int*)(ws + 29600000);           //        256 B
  int*   boff  = (int*)(ws + 29601024);           //        256 B
  // total ws use ~29.6 MB

  hipMemsetAsync(deg, 0, (size_t)NN * sizeof(int), stream);

  k_front<<<PA_BLOCKS + DEG_BLOCKS, 256, 0, stream>>>(
      h, W_fc, attn, edst, z, zb, s1, s2, deg, rank);
  k_scan1<<<NB, 1024, 0, stream>>>(deg, offL, bsum);
  k_scan2<<<1, 64, 0, stream>>>(bsum, boff);
  k_attn_scatter<<<EE * 16 / 256, 256, 0, stream>>>(
      r_h, attn, esrc, edst, s1, s2, rank, offL, boff, pairs);
  k_agg<<<NN / 4, 256, 0, stream>>>(z, zb, pairs, offL, boff, deg, LW, out);
}

// Round 5
// 422.811 us; speedup vs baseline: 1.3199x; 1.0198x over previous
//
#include <hip/hip_runtime.h>
#include <hip/hip_bf16.h>

#define NN 50000
#define EE 800000
#define IND 128
#define OUTD 64
#define NB 49           // ceil(NN/1024) scan blocks
#define PA_BLOCKS 782   // ceil(NN/64) GEMM blocks
#define DEG_BLOCKS 391  // ceil(EE/2048) deg blocks
#define RH_BLOCKS 25000 // EE*16/512 r_h-stream blocks (2 float4 per thread)

// ---------------- Front (fused, 3 block ranges) ----------------------------
// [0,782):        z = h@W_fc^T (bf16 out), s1 = z.w1, s2 = z.w2  (VALU-bound)
// [782,1173):     deg/rank count: rank[e] = atomicAdd(&deg[edst[e]],1)
// [1173,26173):   d3[e] = r_h[e]·w3  (the 204.8 MB HBM stream — overlaps the
//                 VALU-bound GEMM instead of sitting in the CSR serial chain)
__global__ __launch_bounds__(256) void k_front(
    const float* __restrict__ h, const float* __restrict__ W,
    const float* __restrict__ attn, const int* __restrict__ edst,
    const float* __restrict__ r_h,
    __hip_bfloat16* __restrict__ zb, float* __restrict__ s1,
    float* __restrict__ s2, int* __restrict__ deg, int* __restrict__ rank,
    float* __restrict__ d3) {
  const int tid = threadIdx.x;
  if (blockIdx.x >= PA_BLOCKS + DEG_BLOCKS) {  // ---- r_h·w3 stream
    const int base = (blockIdx.x - (PA_BLOCKS + DEG_BLOCKS)) * 512 + tid;
    const int sub = tid & 15;
    float4 rv0 = reinterpret_cast<const float4*>(r_h)[base];
    float4 rv1 = reinterpret_cast<const float4*>(r_h)[base + 256];
    float4 wv = reinterpret_cast<const float4*>(attn + 2 * OUTD)[sub];
    float d0 = rv0.x * wv.x + rv0.y * wv.y + rv0.z * wv.z + rv0.w * wv.w;
    float d1 = rv1.x * wv.x + rv1.y * wv.y + rv1.z * wv.z + rv1.w * wv.w;
#pragma unroll
    for (int m = 1; m <= 8; m <<= 1) {
      d0 += __shfl_xor(d0, m, 64);
      d1 += __shfl_xor(d1, m, 64);
    }
    if (sub == 0) {
      d3[base >> 4] = d0;
      d3[(base >> 4) + 16] = d1;
    }
    return;
  }
  if (blockIdx.x >= PA_BLOCKS) {  // ---- deg/rank
    const int base = (blockIdx.x - PA_BLOCKS) * 2048 + tid;
#pragma unroll
    for (int j = 0; j < 8; ++j) {
      int e = base + j * 256;
      if (e < EE) rank[e] = atomicAdd(&deg[edst[e]], 1);
    }
    return;
  }
  // ---- GEMM: lane l owns output col l; W[l][:] in 128 VGPRs (LDS-staged);
  // h row broadcast via v_readlane; 4 accumulator chains for FMA-latency ILP.
  __shared__ float Wl[64 * 129];
#pragma unroll
  for (int j = 0; j < 8; ++j) {
    int i4 = tid + j * 256;
    const float4 v = reinterpret_cast<const float4*>(W)[i4];
    int i = i4 * 4;
    int col = i >> 7, k = i & 127;
    float* p = &Wl[col * 129 + k];
    p[0] = v.x; p[1] = v.y; p[2] = v.z; p[3] = v.w;
  }
  __syncthreads();
  const int lane = tid & 63;
  const int wid = tid >> 6;
  float Wreg[128];
#pragma unroll
  for (int k = 0; k < 128; ++k) Wreg[k] = Wl[lane * 129 + k];
  const float w1v = attn[lane];
  const float w2v = attn[64 + lane];
  const int base = blockIdx.x * 64 + wid * 16;
  for (int i = 0; i < 16; ++i) {
    int r = base + i;
    if (r >= NN) return;  // wave-uniform
    const float* hr = h + (size_t)r * IND;
    float h0 = hr[lane];
    float h1 = hr[64 + lane];
    float a0 = 0.f, a1 = 0.f, a2 = 0.f, a3 = 0.f;
#pragma unroll
    for (int k = 0; k < 16; ++k) {
      a0 = fmaf(__uint_as_float(__builtin_amdgcn_readlane(__float_as_uint(h0), 4 * k)),     Wreg[4 * k], a0);
      a1 = fmaf(__uint_as_float(__builtin_amdgcn_readlane(__float_as_uint(h0), 4 * k + 1)), Wreg[4 * k + 1], a1);
      a2 = fmaf(__uint_as_float(__builtin_amdgcn_readlane(__float_as_uint(h0), 4 * k + 2)), Wreg[4 * k + 2], a2);
      a3 = fmaf(__uint_as_float(__builtin_amdgcn_readlane(__float_as_uint(h0), 4 * k + 3)), Wreg[4 * k + 3], a3);
    }
#pragma unroll
    for (int k = 0; k < 16; ++k) {
      a0 = fmaf(__uint_as_float(__builtin_amdgcn_readlane(__float_as_uint(h1), 4 * k)),     Wreg[64 + 4 * k], a0);
      a1 = fmaf(__uint_as_float(__builtin_amdgcn_readlane(__float_as_uint(h1), 4 * k + 1)), Wreg[64 + 4 * k + 1], a1);
      a2 = fmaf(__uint_as_float(__builtin_amdgcn_readlane(__float_as_uint(h1), 4 * k + 2)), Wreg[64 + 4 * k + 2], a2);
      a3 = fmaf(__uint_as_float(__builtin_amdgcn_readlane(__float_as_uint(h1), 4 * k + 3)), Wreg[64 + 4 * k + 3], a3);
    }
    float acc = (a0 + a1) + (a2 + a3);
    zb[(size_t)r * OUTD + lane] = __float2bfloat16(acc);
    float p = acc * w1v, q = acc * w2v;
#pragma unroll
    for (int m = 32; m >= 1; m >>= 1) {
      p += __shfl_xor(p, m, 64);
      q += __shfl_xor(q, m, 64);
    }
    if (lane == 0) { s1[r] = p; s2[r] = q; }
  }
}

// ---------------- Scan: exclusive prefix over deg (CSR offsets) ------------
__global__ __launch_bounds__(1024) void k_scan1(
    const int* __restrict__ deg, int* __restrict__ offL,
    int* __restrict__ blocksum) {
  __shared__ int wsum[16];
  __shared__ int woff[17];
  const int tid = threadIdx.x;
  const int gid = blockIdx.x * 1024 + tid;
  const int lane = tid & 63, wid = tid >> 6;
  int v = (gid < NN) ? deg[gid] : 0;
  int incl = v;
#pragma unroll
  for (int o = 1; o < 64; o <<= 1) {
    int t = __shfl_up(incl, o, 64);
    if (lane >= o) incl += t;
  }
  if (lane == 63) wsum[wid] = incl;
  __syncthreads();
  if (wid == 0 && lane < 16) {
    int s = wsum[lane];
    int si = s;
#pragma unroll
    for (int o = 1; o < 16; o <<= 1) {
      int t = __shfl_up(si, o, 64);
      if (lane >= o) si += t;
    }
    woff[lane] = si - s;
    if (lane == 15) woff[16] = si;
  }
  __syncthreads();
  if (gid < NN) offL[gid] = woff[wid] + incl - v;
  if (tid == 0) blocksum[blockIdx.x] = woff[16];
}

__global__ __launch_bounds__(64) void k_scan2(
    const int* __restrict__ blocksum, int* __restrict__ blockoff) {
  const int lane = threadIdx.x;
  int v = (lane < NB) ? blocksum[lane] : 0;
  int incl = v;
#pragma unroll
  for (int o = 1; o < 64; o <<= 1) {
    int t = __shfl_up(incl, o, 64);
    if (lane >= o) incl += t;
  }
  if (lane < NB) blockoff[lane] = incl - v;
}

// ---------------- Scatter (light): 1 thread/edge ---------------------------
// ee = exp(leaky(s1[src]+s2[dst]+d3[e])); pairs[off[dst]+rank[e]] = (src,ee).
// All inputs coalesced streams or L2-hot 200KB gathers; no r_h traffic.
// No seg_max subtraction: |a| small, exp safe in f32; alpha identical.
__global__ __launch_bounds__(256) void k_scatter(
    const int* __restrict__ esrc, const int* __restrict__ edst,
    const float* __restrict__ d3, const float* __restrict__ s1,
    const float* __restrict__ s2, const int* __restrict__ rank,
    const int* __restrict__ offL, const int* __restrict__ blockoff,
    int2* __restrict__ pairs) {
  const int e = blockIdx.x * 256 + threadIdx.x;
  if (e >= EE) return;
  int s = esrc[e], dd = edst[e];
  float a = s1[s] + s2[dd] + d3[e];
  float el = a > 0.f ? a : 0.01f * a;
  float ex = __expf(el);
  int pos = blockoff[dd >> 10] + offL[dd] + rank[e];
  pairs[pos] = make_int2(s, __float_as_int(ex));
}

// ---------------- Agg: gather per dst node ---------------------------------
// One wave per node. lane = (slot = lane>>4, sub = lane&15): slot indexes
// edges, sub the channel-quad. Gathers bf16 zb rows (128 B); 16 edges per
// mega-iteration -> 8 loads in flight/lane. Loop-weight epilogue also bf16.
__global__ __launch_bounds__(256) void k_agg(
    const __hip_bfloat16* __restrict__ zb, const int2* __restrict__ pairs,
    const int* __restrict__ offL, const int* __restrict__ blockoff,
    const int* __restrict__ deg, const float* __restrict__ LW,
    float* __restrict__ out) {
  const int lane = threadIdx.x & 63, wid = threadIdx.x >> 6;
  const int slot = lane >> 4, sub = lane & 15;
  float4 LWreg[16];  // LW[slot*16+kl][4*sub..4*sub+3]
#pragma unroll
  for (int kl = 0; kl < 16; ++kl)
    LWreg[kl] = reinterpret_cast<const float4*>(LW)[(slot * 16 + kl) * 16 + sub];
  const int r = blockIdx.x * 4 + wid;  // grid exact: 12500*4 = 50000
  const int cnt = deg[r];
  const int2* pp = pairs + (blockoff[r >> 10] + offL[r]);
  float4 acc = make_float4(0.f, 0.f, 0.f, 0.f);
  float wsum = 0.f;
  for (int i = 0; i < cnt; i += 16) {
    int2 p[4];
    float w[4];
#pragma unroll
    for (int j = 0; j < 4; ++j) {
      int e = i + j * 4 + slot;
      bool v = e < cnt;
      p[j] = pp[v ? e : 0];  // pp[0] valid: loop entered => cnt >= 1
      w[j] = v ? __int_as_float(p[j].y) : 0.f;
    }
#pragma unroll
    for (int j = 0; j < 4; ++j) {
      ushort4 uz = reinterpret_cast<const ushort4*>(zb)[(size_t)p[j].x * 16 + sub];
      acc.x = fmaf(w[j], __uint_as_float((unsigned)uz.x << 16), acc.x);
      acc.y = fmaf(w[j], __uint_as_float((unsigned)uz.y << 16), acc.y);
      acc.z = fmaf(w[j], __uint_as_float((unsigned)uz.z << 16), acc.z);
      acc.w = fmaf(w[j], __uint_as_float((unsigned)uz.w << 16), acc.w);
      wsum += w[j];
    }
  }
  // loop-weight partial: k in [slot*16, slot*16+16)
  float4 lacc = make_float4(0.f, 0.f, 0.f, 0.f);
#pragma unroll
  for (int j = 0; j < 4; ++j) {
    ushort4 uz = reinterpret_cast<const ushort4*>(zb)[(size_t)r * 16 + slot * 4 + j];
    float zk[4] = {__uint_as_float((unsigned)uz.x << 16),
                   __uint_as_float((unsigned)uz.y << 16),
                   __uint_as_float((unsigned)uz.z << 16),
                   __uint_as_float((unsigned)uz.w << 16)};
#pragma unroll
    for (int c = 0; c < 4; ++c) {
      float4 lw = LWreg[4 * j + c];
      lacc.x = fmaf(zk[c], lw.x, lacc.x);
      lacc.y = fmaf(zk[c], lw.y, lacc.y);
      lacc.z = fmaf(zk[c], lw.z, lacc.z);
      lacc.w = fmaf(zk[c], lw.w, lacc.w);
    }
  }
  wsum += __shfl_xor(wsum, 16, 64);
  wsum += __shfl_xor(wsum, 32, 64);
  float inv = (cnt > 0) ? 1.f / wsum : 0.f;
  float4 t;
  t.x = fmaf(acc.x, inv, lacc.x);
  t.y = fmaf(acc.y, inv, lacc.y);
  t.z = fmaf(acc.z, inv, lacc.z);
  t.w = fmaf(acc.w, inv, lacc.w);
  t.x += __shfl_xor(t.x, 16, 64); t.x += __shfl_xor(t.x, 32, 64);
  t.y += __shfl_xor(t.y, 16, 64); t.y += __shfl_xor(t.y, 32, 64);
  t.z += __shfl_xor(t.z, 16, 64); t.z += __shfl_xor(t.z, 32, 64);
  t.w += __shfl_xor(t.w, 16, 64); t.w += __shfl_xor(t.w, 32, 64);
  if (slot == 0) {
    float4 res;
    res.x = (cnt > 0 && t.x > 0.f) ? t.x : 0.f;
    res.y = (cnt > 0 && t.y > 0.f) ? t.y : 0.f;
    res.z = (cnt > 0 && t.z > 0.f) ? t.z : 0.f;
    res.w = (cnt > 0 && t.w > 0.f) ? t.w : 0.f;
    reinterpret_cast<float4*>(out)[(size_t)r * 16 + sub] = res;
  }
}

extern "C" void kernel_launch(void* const* d_in, const int* in_sizes, int n_in,
                              void* d_out, int out_size, void* d_ws, size_t ws_size,
                              hipStream_t stream) {
  const float* h    = (const float*)d_in[0];  // [N,128]
  const float* r_h  = (const float*)d_in[1];  // [E,64]
  const float* W_fc = (const float*)d_in[2];  // [64,128]
  const float* attn = (const float*)d_in[3];  // [1,192]
  const float* LW   = (const float*)d_in[4];  // [64,64]
  const int* esrc   = (const int*)d_in[5];    // [E]
  const int* edst   = (const int*)d_in[6];    // [E]
  float* out = (float*)d_out;                 // [N,64]

  char* ws = (char*)d_ws;
  __hip_bfloat16* zb = (__hip_bfloat16*)(ws);  //  6,400,000 B
  int2*  pairs = (int2*)(ws + 6400000);        //  6,400,000 B
  int*   rank  = (int*)(ws + 12800000);        //  3,200,000 B
  float* d3    = (float*)(ws + 16000000);      //  3,200,000 B
  float* s1    = (float*)(ws + 19200000);      //    200,000 B
  float* s2    = (float*)(ws + 19400000);      //    200,000 B
  int*   deg   = (int*)(ws + 19600000);        //    200,000 B
  int*   offL  = (int*)(ws + 19800000);        //    200,000 B
  int*   bsum  = (int*)(ws + 20000000);        //        256 B
  int*   boff  = (int*)(ws + 20001024);        //        256 B
  // total ws use ~20 MB

  hipMemsetAsync(deg, 0, (size_t)NN * sizeof(int), stream);

  k_front<<<PA_BLOCKS + DEG_BLOCKS + RH_BLOCKS, 256, 0, stream>>>(
      h, W_fc, attn, edst, r_h, zb, s1, s2, deg, rank, d3);
  k_scan1<<<NB, 1024, 0, stream>>>(deg, offL, bsum);
  k_scan2<<<1, 64, 0, stream>>>(bsum, boff);
  k_scatter<<<(EE + 255) / 256, 256, 0, stream>>>(
      esrc, edst, d3, s1, s2, rank, offL, boff, pairs);
  k_agg<<<NN / 4, 256, 0, stream>>>(zb, pairs, offL, boff, deg, LW, out);
}